// Round 1
// 772.968 us; speedup vs baseline: 1.0720x; 1.0720x over previous
//
#include <hip/hip_runtime.h>
#include <cstdio>
#include <cstdint>

// ---------------------------------------------------------------------------
// MultiHeadSelfAttention (B=2, L=2048, D=512, H=8), per-head full-DxD projs.
// R4 = R3 + (a) pipelined fused_ctx: dbuf Bs/Pb, DMA one tile ahead, single
//      s_barrier per tile with counted s_waitcnt vmcnt(4) (attn stores never
//      drained), setprio around MFMA; (b) 2-way LDS swizzle f=(row>>1)&3;
//      (c) softmax row-stats fused into scores epilogue (partials + combine),
//      row_stats full 268MB re-read eliminated.
// ---------------------------------------------------------------------------

#define AS1 __attribute__((address_space(1)))
#define AS3 __attribute__((address_space(3)))

typedef __attribute__((ext_vector_type(8))) short bf16x8;   // 8 bf16 = 4 VGPRs
typedef __attribute__((ext_vector_type(4))) short short4v;  // 4 bf16 = 8 B
typedef __attribute__((ext_vector_type(4))) float f32x4;    // MFMA acc

constexpr int cB = 2, cH = 8, cL = 2048, cD = 512;
constexpr float SCORE_SCALE = 0.044194173824159216f; // 1/sqrt(512)

__device__ __forceinline__ short f2bf(float f) {
  return __builtin_bit_cast(short, static_cast<__bf16>(f)); // RNE convert
}

__device__ __forceinline__ void gload16(const void* g, void* l) {
  // async global->LDS, 16B per lane; LDS dest is wave-uniform base + lane*16
  __builtin_amdgcn_global_load_lds((AS1 const void*)g, (AS3 void*)l, 16, 0, 0);
}

// --------------------------- fp32 -> bf16 convert (merged) ------------------
struct CvtArgs { const float4* s[7]; short4v* d[7]; };

__global__ __launch_bounds__(256) void cvt_all(CvtArgs a) {
  const int z = blockIdx.y;
  const int i = blockIdx.x * 256 + threadIdx.x;
  const float4 v = a.s[z][i];
  short4v o = { f2bf(v.x), f2bf(v.y), f2bf(v.z), f2bf(v.w) };
  a.d[z][i] = o;
}

// ------------------------------- GEMM modes ---------------------------------
enum { M_PROJ = 0, M_PROJV = 1, M_SCORES = 2, M_OUT = 3 };

template <int MODE>
__global__ __launch_bounds__(256) void gemm_nt(const short* __restrict__ Ap,
                                               const short* __restrict__ Bp,
                                               void* __restrict__ Cp,
                                               float2* __restrict__ Sp) {
  constexpr int K   = (MODE == M_OUT) ? 2048 : 512;   // k-loop extent
  constexpr int LDA = (MODE == M_OUT) ? 4096 : 512;   // A row stride
  constexpr int LDB = (MODE == M_OUT) ? 4096 : 512;   // B row stride

  __shared__ short As[128 * 32];  // 8 KB
  __shared__ short Bs[128 * 32];  // 8 KB

  const int t = threadIdx.x;
  const int lane = t & 63;
  const int wv = t >> 6;          // wave 0..3
  const int wm = wv >> 1, wn = wv & 1;
  const int z = blockIdx.z;

  size_t Aoff, Boff;
  if constexpr (MODE == M_PROJ || MODE == M_PROJV) {
    Aoff = (size_t)(z >> 3) * ((size_t)cL * cD);   // per-b input
    Boff = (size_t)(z & 7) * ((size_t)cD * cD);    // per-h weight
  } else if constexpr (MODE == M_SCORES) {
    Aoff = (size_t)z * ((size_t)cL * cD);          // qh[b,h]
    Boff = (size_t)z * ((size_t)cL * cD);          // kh[b,h]
  } else {                                         // M_OUT split-K: z = b*2+khalf
    Aoff = (size_t)(z >> 1) * ((size_t)cL * 4096) + (size_t)(z & 1) * 2048;
    Boff = (size_t)(z & 1) * 2048;
  }

  const short* Ag0 = Ap + Aoff + (size_t)(blockIdx.y * 128) * LDA;
  const short* Bg0 = Bp + Boff + (size_t)(blockIdx.x * 128) * LDB;

  f32x4 acc[4][4];
#pragma unroll
  for (int i = 0; i < 4; ++i)
#pragma unroll
    for (int j = 0; j < 4; ++j) acc[i][j] = (f32x4){0.f, 0.f, 0.f, 0.f};

  for (int kt = 0; kt < K; kt += 32) {
    __syncthreads();  // LDS safe to overwrite
#pragma unroll
    for (int r = 0; r < 2; ++r) {
      const int cbase = r * 256 + wv * 64;    // wave-uniform chunk base
      const int c = cbase + lane;             // 0..511 16B chunks
      const int row = c >> 2, col = (c & 3) * 8;
      gload16(Ag0 + (size_t)row * LDA + kt + col, &As[cbase * 8]);
    }
#pragma unroll
    for (int r = 0; r < 2; ++r) {
      const int cbase = r * 256 + wv * 64;
      const int c = cbase + lane;
      const int row = c >> 2, col = (c & 3) * 8;
      gload16(Bg0 + (size_t)row * LDB + kt + col, &Bs[cbase * 8]);
    }
    __syncthreads();  // staging complete

    const int koff = (lane >> 4) * 8;           // A/B frag: k = quad*8 + j
    const int ar = wm * 64 + (lane & 15);
    const int br = wn * 64 + (lane & 15);
    bf16x8 af[4], bfv[4];
#pragma unroll
    for (int i = 0; i < 4; ++i) af[i] = *(const bf16x8*)&As[(ar + i * 16) * 32 + koff];
#pragma unroll
    for (int j = 0; j < 4; ++j) bfv[j] = *(const bf16x8*)&Bs[(br + j * 16) * 32 + koff];
#pragma unroll
    for (int i = 0; i < 4; ++i)
#pragma unroll
      for (int j = 0; j < 4; ++j)
        acc[i][j] = __builtin_amdgcn_mfma_f32_16x16x32_bf16(af[i], bfv[j], acc[i][j], 0, 0, 0);
  }

  // ---- epilogue: C/D layout col=lane&15, row=(lane>>4)*4+reg ----
  const int r0 = (lane >> 4) * 4;
  const int cc = lane & 15;
  const int rowbase = blockIdx.y * 128 + wm * 64 + r0;
  const int colbase = blockIdx.x * 128 + wn * 64 + cc;

  if constexpr (MODE == M_PROJ) {
    short* C = (short*)Cp + (size_t)z * ((size_t)cL * cD);
#pragma unroll
    for (int i = 0; i < 4; ++i)
#pragma unroll
      for (int j = 0; j < 4; ++j)
#pragma unroll
        for (int r = 0; r < 4; ++r)
          C[(size_t)(rowbase + i * 16 + r) * cD + (colbase + j * 16)] = f2bf(acc[i][j][r]);
  } else if constexpr (MODE == M_PROJV) {
    // store transposed: vhT[e][l]
    short* C = (short*)Cp + (size_t)z * ((size_t)cD * cL);
#pragma unroll
    for (int i = 0; i < 4; ++i)
#pragma unroll
      for (int j = 0; j < 4; ++j) {
        short4v o = { f2bf(acc[i][j][0]), f2bf(acc[i][j][1]),
                      f2bf(acc[i][j][2]), f2bf(acc[i][j][3]) };
        *(short4v*)&C[(size_t)(colbase + j * 16) * cL + (rowbase + i * 16)] = o;
      }
  } else if constexpr (MODE == M_SCORES) {
    float* C = (float*)Cp + (size_t)z * ((size_t)cL * cL);
    float2* ps = Sp + (size_t)z * ((size_t)cL * 32);
    const int pid = blockIdx.x * 2 + wn;  // 0..31: which 64-col slice
#pragma unroll
    for (int i = 0; i < 4; ++i) {
      float sv[4][4];
#pragma unroll
      for (int j = 0; j < 4; ++j)
#pragma unroll
        for (int r = 0; r < 4; ++r) sv[j][r] = acc[i][j][r] * SCORE_SCALE;
#pragma unroll
      for (int j = 0; j < 4; ++j)
#pragma unroll
        for (int r = 0; r < 4; ++r)
          C[(size_t)(rowbase + i * 16 + r) * cL + (colbase + j * 16)] = sv[j][r];
      // per-row partial (max, sum-exp) over this wave's 64 cols:
      // reduce over j in-register, then over cc (16-lane group, xor 1,2,4,8)
#pragma unroll
      for (int r = 0; r < 4; ++r) {
        float mx = fmaxf(fmaxf(sv[0][r], sv[1][r]), fmaxf(sv[2][r], sv[3][r]));
#pragma unroll
        for (int off = 1; off < 16; off <<= 1) mx = fmaxf(mx, __shfl_xor(mx, off, 64));
        float sm = __expf(sv[0][r] - mx) + __expf(sv[1][r] - mx) +
                   __expf(sv[2][r] - mx) + __expf(sv[3][r] - mx);
#pragma unroll
        for (int off = 1; off < 16; off <<= 1) sm += __shfl_xor(sm, off, 64);
        if ((lane & 15) == 0)
          ps[(size_t)(rowbase + i * 16 + r) * 32 + pid] = make_float2(mx, sm);
      }
    }
  } else {  // M_OUT: fp32 partial (khalf) into ws
    float* C = (float*)Cp + (size_t)((z & 1) * 2 + (z >> 1)) * ((size_t)cL * cD);
#pragma unroll
    for (int i = 0; i < 4; ++i)
#pragma unroll
      for (int j = 0; j < 4; ++j)
#pragma unroll
        for (int r = 0; r < 4; ++r)
          C[(size_t)(rowbase + i * 16 + r) * cD + (colbase + j * 16)] = acc[i][j][r];
  }
}

// ------------- combine per-block softmax partials -> (m, 1/l) ---------------
__global__ __launch_bounds__(256) void combine_stats(const float2* __restrict__ ps,
                                                     float2* __restrict__ stats) {
  const int row = blockIdx.x * 256 + threadIdx.x;  // 0..32767
  const float2* p = ps + (size_t)row * 32;
  float m = -1e30f;
#pragma unroll
  for (int i = 0; i < 32; ++i) m = fmaxf(m, p[i].x);
  float l = 0.f;
#pragma unroll
  for (int i = 0; i < 32; ++i) l += p[i].y * __expf(p[i].x - m);
  stats[row] = make_float2(m, 1.0f / l);
}

// ---------------- fused softmax-normalize (in place) + ctx ------------------
// grid (rowblk=16, z=16), 512 threads = 8 waves (2M x 4N), wave tile 64x128.
// Pipelined: double-buffered Bs/Pb, DMA one tile ahead, ONE s_barrier/tile,
// counted s_waitcnt vmcnt(4) (this iter's 2 attn stores + 2 prefetch loads
// stay in flight; in-order vmcnt retirement => tile-k DMA complete).
__global__ __launch_bounds__(512) void fused_ctx(const short* __restrict__ vhT,
                                                 const float2* __restrict__ stats,
                                                 float* __restrict__ attn,
                                                 short* __restrict__ comb) {
  __shared__ short Bs[2][512 * 32];  // 64 KB vhT tiles (dbuf), swizzled
  __shared__ short Pb[2][128 * 32];  // 16 KB P bf16 (dbuf), swizzled

  const int t = threadIdx.x;
  const int lane = t & 63;
  const int wv = t >> 6;          // 0..7
  const int wm = wv >> 2, wn = wv & 3;
  const int rowblk = blockIdx.x;  // 0..15
  const int z = blockIdx.y;       // b*8+h

  // transform-thread coords: thread owns (row = t>>2, 8-col chunk (t&3) per tile)
  const int trow = t >> 2;                       // 0..127
  const int tcb = t & 3;
  const int tslot = tcb ^ ((trow >> 1) & 3);     // 2-way-free swizzle slot
  const int grow = rowblk * 128 + trow;
  float* sp = attn + ((size_t)z * cL + grow) * cL + tcb * 8;
  const float2 st = stats[(size_t)z * cL + grow];
  const float m = st.x, invl = st.y;

  const short* Bg = vhT + (size_t)z * ((size_t)cD * cL);

  f32x4 acc[4][8];
#pragma unroll
  for (int i = 0; i < 4; ++i)
#pragma unroll
    for (int j = 0; j < 8; ++j) acc[i][j] = (f32x4){0.f, 0.f, 0.f, 0.f};

  const int qk = lane >> 4;                  // frag k-chunk 0..3
  const int ar = wm * 64 + (lane & 15);
  const int br = wn * 128 + (lane & 15);

  auto stageB = [&](int nb, int kt) {
#pragma unroll
    for (int r = 0; r < 4; ++r) {
      const int cbase = r * 512 + wv * 64;   // wave-uniform base
      const int c = cbase + lane;            // 0..2047 16B chunks
      const int row = c >> 2;
      const int swcol = ((c & 3) ^ ((row >> 1) & 3)) * 8;  // source pre-swizzle
      gload16(Bg + (size_t)row * cL + kt + swcol, &Bs[nb][cbase * 8]);
    }
  };
  auto transform = [&](int ck, float4 v0, float4 v1) -> bf16x8 {
    float* dst = sp + ck * 32;
    const float p0 = __expf(v0.x - m) * invl;
    const float p1 = __expf(v0.y - m) * invl;
    const float p2 = __expf(v0.z - m) * invl;
    const float p3 = __expf(v0.w - m) * invl;
    const float p4 = __expf(v1.x - m) * invl;
    const float p5 = __expf(v1.y - m) * invl;
    const float p6 = __expf(v1.z - m) * invl;
    const float p7 = __expf(v1.w - m) * invl;
    *(float4*)(dst)     = make_float4(p0, p1, p2, p3);
    *(float4*)(dst + 4) = make_float4(p4, p5, p6, p7);
    bf16x8 pb = { f2bf(p0), f2bf(p1), f2bf(p2), f2bf(p3),
                  f2bf(p4), f2bf(p5), f2bf(p6), f2bf(p7) };
    return pb;
  };

  // ---- prologue: DMA tile 0; transform chunk 0 -> Pb[0] ----
  stageB(0, 0);
  float4 c0 = *(const float4*)(sp);
  float4 c1 = *(const float4*)(sp + 4);
  bf16x8 pb = transform(0, c0, c1);
  c0 = *(const float4*)(sp + 32);
  c1 = *(const float4*)(sp + 36);
  *(bf16x8*)&Pb[0][trow * 32 + tslot * 8] = pb;

  for (int k = 0; k < 63; ++k) {
    const int cb = k & 1, nb = cb ^ 1;
    // s1: transform chunk k+1 (VALU + 2 attn stores), prefetch chunk (k+2)&63
    pb = transform(k + 1, c0, c1);
    const int kc = (k + 2) & 63;   // k=62 wraps to chunk 0: dead load, keeps count
    c0 = *(const float4*)(sp + kc * 32);
    c1 = *(const float4*)(sp + kc * 32 + 4);
    // s2: tile-k DMA done (4 newest vm ops = this iter's 2 stores + 2 loads);
    //     my Pb write from prev iter drained for barrier visibility
    asm volatile("s_waitcnt vmcnt(4) lgkmcnt(0)" ::: "memory");
    __builtin_amdgcn_sched_barrier(0);
    // s3: the ONLY barrier per tile (no vmcnt(0) drain)
    __builtin_amdgcn_s_barrier();
    __builtin_amdgcn_sched_barrier(0);
    // s4: publish P tile k+1 (readers are behind next barrier)
    *(bf16x8*)&Pb[nb][trow * 32 + tslot * 8] = pb;
    // s5: DMA tile k+1 (WAR-safe: all tile-k-1 readers passed this barrier)
    stageB(nb, (k + 1) * 32);
    __builtin_amdgcn_sched_barrier(0);  // pin DMA before s6/s1': vmcnt(4) has 0 slack
    // s6: compute tile k
    bf16x8 af[4], bfv[8];
#pragma unroll
    for (int i = 0; i < 4; ++i) {
      const int rA = ar + i * 16;
      af[i] = *(const bf16x8*)&Pb[cb][rA * 32 + (qk ^ ((rA >> 1) & 3)) * 8];
    }
#pragma unroll
    for (int j = 0; j < 8; ++j) {
      const int rB = br + j * 16;
      bfv[j] = *(const bf16x8*)&Bs[cb][rB * 32 + (qk ^ ((rB >> 1) & 3)) * 8];
    }
    __builtin_amdgcn_s_setprio(1);
#pragma unroll
    for (int i = 0; i < 4; ++i)
#pragma unroll
      for (int j = 0; j < 8; ++j)
        acc[i][j] = __builtin_amdgcn_mfma_f32_16x16x32_bf16(af[i], bfv[j], acc[i][j], 0, 0, 0);
    __builtin_amdgcn_s_setprio(0);
  }

  // ---- peeled tile 63 (buffers 1) ----
  asm volatile("s_waitcnt vmcnt(0) lgkmcnt(0)" ::: "memory");
  __builtin_amdgcn_sched_barrier(0);
  __builtin_amdgcn_s_barrier();
  __builtin_amdgcn_sched_barrier(0);
  {
    bf16x8 af[4], bfv[8];
#pragma unroll
    for (int i = 0; i < 4; ++i) {
      const int rA = ar + i * 16;
      af[i] = *(const bf16x8*)&Pb[1][rA * 32 + (qk ^ ((rA >> 1) & 3)) * 8];
    }
#pragma unroll
    for (int j = 0; j < 8; ++j) {
      const int rB = br + j * 16;
      bfv[j] = *(const bf16x8*)&Bs[1][rB * 32 + (qk ^ ((rB >> 1) & 3)) * 8];
    }
    __builtin_amdgcn_s_setprio(1);
#pragma unroll
    for (int i = 0; i < 4; ++i)
#pragma unroll
      for (int j = 0; j < 8; ++j)
        acc[i][j] = __builtin_amdgcn_mfma_f32_16x16x32_bf16(af[i], bfv[j], acc[i][j], 0, 0, 0);
    __builtin_amdgcn_s_setprio(0);
  }

  // ---- epilogue -> comb permuted layout: j = (e>>6)*512 + h*64 + (e&63) ----
  const int r0 = (lane >> 4) * 4;
  const int cc = lane & 15;
  short* C = comb + (size_t)(z >> 3) * ((size_t)cL * (cH * cD));
  const int h = z & 7;
  const int rowbase = rowblk * 128 + wm * 64 + r0;
#pragma unroll
  for (int i = 0; i < 4; ++i)
#pragma unroll
    for (int j = 0; j < 8; ++j) {
      const int e = wn * 128 + j * 16 + cc;
      const int jc = ((e >> 6) << 9) + (h << 6) + (e & 63);
#pragma unroll
      for (int r = 0; r < 4; ++r)
        C[(size_t)(rowbase + i * 16 + r) * (cH * cD) + jc] = f2bf(acc[i][j][r]);
    }
}

// --------------------- sum the two split-K partials -------------------------
__global__ __launch_bounds__(256) void add_halves(const float4* __restrict__ p,
                                                  float4* __restrict__ out) {
  const int i = blockIdx.x * 256 + threadIdx.x;
  const float4 a = p[i];
  const float4 b = p[i + (cB * cL * cD) / 4];
  out[i] = make_float4(a.x + b.x, a.y + b.y, a.z + b.z, a.w + b.w);
}

// --------------------------------- launch -----------------------------------
extern "C" void kernel_launch(void* const* d_in, const int* in_sizes, int n_in,
                              void* d_out, int out_size, void* d_ws, size_t ws_size,
                              hipStream_t stream) {
  (void)in_sizes; (void)n_in; (void)out_size;

  const float* q  = (const float*)d_in[0];
  const float* k  = (const float*)d_in[1];
  const float* v  = (const float*)d_in[2];
  const float* Wq = (const float*)d_in[3];
  const float* Wk = (const float*)d_in[4];
  const float* Wv = (const float*)d_in[5];
  const float* Wo = (const float*)d_in[6];

  float* out  = (float*)d_out;
  float* attn = out + (size_t)cB * cL * cD;  // 2,097,152 floats in

  constexpr size_t Mi = 1ull << 20;
  char* ws = (char*)d_ws;
  short* qbf = (short*)(ws + 0 * Mi);
  short* kbf = (short*)(ws + 4 * Mi);
  short* vbf = (short*)(ws + 8 * Mi);
  short* wqb = (short*)(ws + 12 * Mi);
  short* wkb = (short*)(ws + 16 * Mi);
  short* wvb = (short*)(ws + 20 * Mi);
  short* wob = (short*)(ws + 24 * Mi);
  short* qh  = (short*)(ws + 28 * Mi);   // 32 MiB; dead after scores
  short* kh  = (short*)(ws + 60 * Mi);   // 32 MiB; dead after scores
  short* vhT = (short*)(ws + 92 * Mi);   // 32 MiB
  short* comb = qh;                      // alias: written after qh dead
  float2* stats  = (float2*)(ws + 0 * Mi);  // alias qbf (dead after projections)
  float2* pstats = (float2*)(ws + 4 * Mi);  // 8 MiB, alias kbf+vbf (dead after proj)
  float*  pout   = (float*)(ws + 60 * Mi);  // alias kh (dead after scores), 16 MiB

  if (ws_size < 124 * Mi) {
    fprintf(stderr, "kernel_launch: ws too small (%zu < %zu)\n", ws_size, 124 * Mi);
    return;
  }

  // 1) convert inputs/weights to bf16 (7 same-size tensors, one launch)
  CvtArgs ca;
  ca.s[0] = (const float4*)q;  ca.d[0] = (short4v*)qbf;
  ca.s[1] = (const float4*)k;  ca.d[1] = (short4v*)kbf;
  ca.s[2] = (const float4*)v;  ca.d[2] = (short4v*)vbf;
  ca.s[3] = (const float4*)Wq; ca.d[3] = (short4v*)wqb;
  ca.s[4] = (const float4*)Wk; ca.d[4] = (short4v*)wkb;
  ca.s[5] = (const float4*)Wv; ca.d[5] = (short4v*)wvb;
  ca.s[6] = (const float4*)Wo; ca.d[6] = (short4v*)wob;
  cvt_all<<<dim3(2048, 7), 256, 0, stream>>>(ca);

  // 2) per-head projections (z = b*8+h), M=2048 N=512 K=512
  gemm_nt<M_PROJ ><<<dim3(4, 16, 16), 256, 0, stream>>>(qbf, wqb, qh, nullptr);
  gemm_nt<M_PROJ ><<<dim3(4, 16, 16), 256, 0, stream>>>(kbf, wkb, kh, nullptr);
  gemm_nt<M_PROJV><<<dim3(4, 16, 16), 256, 0, stream>>>(vbf, wvb, vhT, nullptr);

  // 3) scores -> d_out attn region (fp32, scaled) + per-block row stats partials
  gemm_nt<M_SCORES><<<dim3(16, 16, 16), 256, 0, stream>>>(qh, kh, attn, pstats);

  // 4) combine partials -> (m, 1/l) per row (replaces 268MB row_stats re-read)
  combine_stats<<<cB * cH * cL / 256, 256, 0, stream>>>(pstats, stats);

  // 5) fused: normalize attn in place + ctx -> comb (pipelined)
  fused_ctx<<<dim3(16, cB * cH), 512, 0, stream>>>(vhT, stats, attn, comb);

  // 6) out = comb @ Wo^T, split-K x2 (z = b*2 + khalf) -> fp32 partials
  gemm_nt<M_OUT><<<dim3(4, 16, 4), 256, 0, stream>>>(comb, wob, (void*)pout, nullptr);

  // 7) out = partial0 + partial1
  add_halves<<<2048, 256, 0, stream>>>((const float4*)pout, (float4*)out);
}

// Round 3
// 740.470 us; speedup vs baseline: 1.1190x; 1.0439x over previous
//
#include <hip/hip_runtime.h>
#include <cstdio>
#include <cstdint>

// ---------------------------------------------------------------------------
// MultiHeadSelfAttention (B=2, L=2048, D=512, H=8), per-head full-DxD projs.
// R6 = R5 resubmission (previous bench died at container level - infra flake;
//      kernel re-audited: no divergent barriers, vmcnt counts safe, bounds ok).
// R5 = R4 + (a) fused_ctx restructured to 64-row blocks (grid 32x16 = 512
//      blocks = 2 blocks/CU, LDS 72KB, launch_bounds(512,4) caps regs for 16
//      waves/CU); (b) gemm_nt triple-buffered with counted vmcnt(4), stage
//      issued 2 tiles ahead post-barrier; (c) M_OUT split-K x4 + add_quads.
// ---------------------------------------------------------------------------

#define AS1 __attribute__((address_space(1)))
#define AS3 __attribute__((address_space(3)))

typedef __attribute__((ext_vector_type(8))) short bf16x8;   // 8 bf16 = 4 VGPRs
typedef __attribute__((ext_vector_type(4))) short short4v;  // 4 bf16 = 8 B
typedef __attribute__((ext_vector_type(4))) float f32x4;    // MFMA acc

constexpr int cB = 2, cH = 8, cL = 2048, cD = 512;
constexpr float SCORE_SCALE = 0.044194173824159216f; // 1/sqrt(512)

__device__ __forceinline__ short f2bf(float f) {
  return __builtin_bit_cast(short, static_cast<__bf16>(f)); // RNE convert
}

__device__ __forceinline__ void gload16(const void* g, void* l) {
  // async global->LDS, 16B per lane; LDS dest is wave-uniform base + lane*16
  __builtin_amdgcn_global_load_lds((AS1 const void*)g, (AS3 void*)l, 16, 0, 0);
}

// --------------------------- fp32 -> bf16 convert (merged) ------------------
struct CvtArgs { const float4* s[7]; short4v* d[7]; };

__global__ __launch_bounds__(256) void cvt_all(CvtArgs a) {
  const int z = blockIdx.y;
  const int i = blockIdx.x * 256 + threadIdx.x;
  const float4 v = a.s[z][i];
  short4v o = { f2bf(v.x), f2bf(v.y), f2bf(v.z), f2bf(v.w) };
  a.d[z][i] = o;
}

// ------------------------------- GEMM modes ---------------------------------
enum { M_PROJ = 0, M_PROJV = 1, M_SCORES = 2, M_OUT = 3 };

template <int MODE>
__global__ __launch_bounds__(256) void gemm_nt(const short* __restrict__ Ap,
                                               const short* __restrict__ Bp,
                                               void* __restrict__ Cp,
                                               float2* __restrict__ Sp) {
  constexpr int K   = (MODE == M_OUT) ? 1024 : 512;   // k-loop extent
  constexpr int LDA = (MODE == M_OUT) ? 4096 : 512;   // A row stride
  constexpr int LDB = (MODE == M_OUT) ? 4096 : 512;   // B row stride

  __shared__ short As[3][128 * 32];  // 24 KB (tri-buffer)
  __shared__ short Bs[3][128 * 32];  // 24 KB

  const int t = threadIdx.x;
  const int lane = t & 63;
  const int wv = t >> 6;          // wave 0..3
  const int wm = wv >> 1, wn = wv & 1;
  const int z = blockIdx.z;

  size_t Aoff, Boff;
  if constexpr (MODE == M_PROJ || MODE == M_PROJV) {
    Aoff = (size_t)(z >> 3) * ((size_t)cL * cD);   // per-b input
    Boff = (size_t)(z & 7) * ((size_t)cD * cD);    // per-h weight
  } else if constexpr (MODE == M_SCORES) {
    Aoff = (size_t)z * ((size_t)cL * cD);          // qh[b,h]
    Boff = (size_t)z * ((size_t)cL * cD);          // kh[b,h]
  } else {                                         // M_OUT split-K x4: z = b*4+kq
    Aoff = (size_t)(z >> 2) * ((size_t)cL * 4096) + (size_t)(z & 3) * 1024;
    Boff = (size_t)(z & 3) * 1024;
  }

  const short* Ag0 = Ap + Aoff + (size_t)(blockIdx.y * 128) * LDA;
  const short* Bg0 = Bp + Boff + (size_t)(blockIdx.x * 128) * LDB;

  f32x4 acc[4][4];
#pragma unroll
  for (int i = 0; i < 4; ++i)
#pragma unroll
    for (int j = 0; j < 4; ++j) acc[i][j] = (f32x4){0.f, 0.f, 0.f, 0.f};

  auto stage = [&](int b, int kt) {
#pragma unroll
    for (int r = 0; r < 2; ++r) {
      const int cbase = r * 256 + wv * 64;    // wave-uniform chunk base
      const int c = cbase + lane;             // 0..511 16B chunks
      const int row = c >> 2, col = (c & 3) * 8;
      gload16(Ag0 + (size_t)row * LDA + kt + col, &As[b][cbase * 8]);
    }
#pragma unroll
    for (int r = 0; r < 2; ++r) {
      const int cbase = r * 256 + wv * 64;
      const int c = cbase + lane;
      const int row = c >> 2, col = (c & 3) * 8;
      gload16(Bg0 + (size_t)row * LDB + kt + col, &Bs[b][cbase * 8]);
    }
  };

  const int koff = (lane >> 4) * 8;           // A/B frag: k = quad*8 + j
  const int ar = wm * 64 + (lane & 15);
  const int br = wn * 64 + (lane & 15);

  constexpr int nt = K / 32;
  stage(0, 0);
  stage(1, 32);
  int cur = 0, pre = 2;
  for (int tt = 0; tt < nt; ++tt) {
    // counted wait: leaves only the newest stage (tt+1) in flight; in-order
    // retirement => stage(tt) complete. Last iter: full drain.
    if (tt < nt - 1) { asm volatile("s_waitcnt vmcnt(4) lgkmcnt(0)" ::: "memory"); }
    else             { asm volatile("s_waitcnt vmcnt(0) lgkmcnt(0)" ::: "memory"); }
    __builtin_amdgcn_sched_barrier(0);
    __builtin_amdgcn_s_barrier();
    __builtin_amdgcn_sched_barrier(0);
    if (tt + 2 < nt) stage(pre, (tt + 2) * 32);  // post-barrier: WAR-safe
    __builtin_amdgcn_sched_barrier(0);

    bf16x8 af[4], bfv[4];
#pragma unroll
    for (int i = 0; i < 4; ++i) af[i] = *(const bf16x8*)&As[cur][(ar + i * 16) * 32 + koff];
#pragma unroll
    for (int j = 0; j < 4; ++j) bfv[j] = *(const bf16x8*)&Bs[cur][(br + j * 16) * 32 + koff];
    __builtin_amdgcn_s_setprio(1);
#pragma unroll
    for (int i = 0; i < 4; ++i)
#pragma unroll
      for (int j = 0; j < 4; ++j)
        acc[i][j] = __builtin_amdgcn_mfma_f32_16x16x32_bf16(af[i], bfv[j], acc[i][j], 0, 0, 0);
    __builtin_amdgcn_s_setprio(0);
    cur = (cur == 2) ? 0 : cur + 1;
    pre = (pre == 2) ? 0 : pre + 1;
  }

  // ---- epilogue: C/D layout col=lane&15, row=(lane>>4)*4+reg ----
  const int r0 = (lane >> 4) * 4;
  const int cc = lane & 15;
  const int rowbase = blockIdx.y * 128 + wm * 64 + r0;
  const int colbase = blockIdx.x * 128 + wn * 64 + cc;

  if constexpr (MODE == M_PROJ) {
    short* C = (short*)Cp + (size_t)z * ((size_t)cL * cD);
#pragma unroll
    for (int i = 0; i < 4; ++i)
#pragma unroll
      for (int j = 0; j < 4; ++j)
#pragma unroll
        for (int r = 0; r < 4; ++r)
          C[(size_t)(rowbase + i * 16 + r) * cD + (colbase + j * 16)] = f2bf(acc[i][j][r]);
  } else if constexpr (MODE == M_PROJV) {
    // store transposed: vhT[e][l]
    short* C = (short*)Cp + (size_t)z * ((size_t)cD * cL);
#pragma unroll
    for (int i = 0; i < 4; ++i)
#pragma unroll
      for (int j = 0; j < 4; ++j) {
        short4v o = { f2bf(acc[i][j][0]), f2bf(acc[i][j][1]),
                      f2bf(acc[i][j][2]), f2bf(acc[i][j][3]) };
        *(short4v*)&C[(size_t)(colbase + j * 16) * cL + (rowbase + i * 16)] = o;
      }
  } else if constexpr (MODE == M_SCORES) {
    float* C = (float*)Cp + (size_t)z * ((size_t)cL * cL);
    float2* ps = Sp + (size_t)z * ((size_t)cL * 32);
    const int pid = blockIdx.x * 2 + wn;  // 0..31: which 64-col slice
#pragma unroll
    for (int i = 0; i < 4; ++i) {
      float sv[4][4];
#pragma unroll
      for (int j = 0; j < 4; ++j)
#pragma unroll
        for (int r = 0; r < 4; ++r) sv[j][r] = acc[i][j][r] * SCORE_SCALE;
#pragma unroll
      for (int j = 0; j < 4; ++j)
#pragma unroll
        for (int r = 0; r < 4; ++r)
          C[(size_t)(rowbase + i * 16 + r) * cL + (colbase + j * 16)] = sv[j][r];
      // per-row partial (max, sum-exp) over this wave's 64 cols
#pragma unroll
      for (int r = 0; r < 4; ++r) {
        float mx = fmaxf(fmaxf(sv[0][r], sv[1][r]), fmaxf(sv[2][r], sv[3][r]));
#pragma unroll
        for (int off = 1; off < 16; off <<= 1) mx = fmaxf(mx, __shfl_xor(mx, off, 64));
        float sm = __expf(sv[0][r] - mx) + __expf(sv[1][r] - mx) +
                   __expf(sv[2][r] - mx) + __expf(sv[3][r] - mx);
#pragma unroll
        for (int off = 1; off < 16; off <<= 1) sm += __shfl_xor(sm, off, 64);
        if ((lane & 15) == 0)
          ps[(size_t)(rowbase + i * 16 + r) * 32 + pid] = make_float2(mx, sm);
      }
    }
  } else {  // M_OUT: fp32 partial (kq) into ws
    float* C = (float*)Cp + (size_t)((z & 3) * 2 + (z >> 2)) * ((size_t)cL * cD);
#pragma unroll
    for (int i = 0; i < 4; ++i)
#pragma unroll
      for (int j = 0; j < 4; ++j)
#pragma unroll
        for (int r = 0; r < 4; ++r)
          C[(size_t)(rowbase + i * 16 + r) * cD + (colbase + j * 16)] = acc[i][j][r];
  }
}

// ------------- combine per-block softmax partials -> (m, 1/l) ---------------
__global__ __launch_bounds__(256) void combine_stats(const float2* __restrict__ ps,
                                                     float2* __restrict__ stats) {
  const int row = blockIdx.x * 256 + threadIdx.x;  // 0..32767
  const float2* p = ps + (size_t)row * 32;
  float m = -1e30f;
#pragma unroll
  for (int i = 0; i < 32; ++i) m = fmaxf(m, p[i].x);
  float l = 0.f;
#pragma unroll
  for (int i = 0; i < 32; ++i) l += p[i].y * __expf(p[i].x - m);
  stats[row] = make_float2(m, 1.0f / l);
}

// ---------------- fused softmax-normalize (in place) + ctx ------------------
// grid (rowblk=32, z=16) = 512 blocks = 2 blocks/CU. 512 threads = 8 N-waves,
// block tile 64 rows x 512 e. Pipelined: dbuf Bs/Pb, DMA one tile ahead, ONE
// s_barrier/tile with counted vmcnt(2) (1 attn store + 1 prefetch load stay
// in flight). launch_bounds(512,4): regs <=128 so both blocks are resident.
__global__ __launch_bounds__(512, 4) void fused_ctx(const short* __restrict__ vhT,
                                                    const float2* __restrict__ stats,
                                                    float* __restrict__ attn,
                                                    short* __restrict__ comb) {
  __shared__ short Bs[2][512 * 32];  // 64 KB vhT tiles (dbuf), swizzled
  __shared__ short Pb[2][64 * 32];   //  8 KB P bf16 (dbuf), swizzled

  const int t = threadIdx.x;
  const int lane = t & 63;
  const int wv = t >> 6;          // 0..7 (N-wave)
  const int rowblk = blockIdx.x;  // 0..31
  const int z = blockIdx.y;       // b*8+h

  // transform-thread coords: thread owns (row = t>>3, float4 chunk t&7 per tile)
  const int trow = t >> 3;                       // 0..63
  const int tcb = t & 7;                         // which float4 in 32-col tile
  const int pidx = trow * 32 + (((tcb >> 1) ^ ((trow >> 1) & 3)) << 3) + ((tcb & 1) << 2);
  const int grow = rowblk * 64 + trow;
  float* sp = attn + ((size_t)z * cL + grow) * cL + tcb * 4;
  const float2 st = stats[(size_t)z * cL + grow];
  const float m = st.x, invl = st.y;

  const short* Bg = vhT + (size_t)z * ((size_t)cD * cL);

  f32x4 acc[4][4];
#pragma unroll
  for (int i = 0; i < 4; ++i)
#pragma unroll
    for (int j = 0; j < 4; ++j) acc[i][j] = (f32x4){0.f, 0.f, 0.f, 0.f};

  const int qk = lane >> 4;                  // frag k-chunk 0..3
  const int arr = lane & 15;
  const int br = wv * 64 + (lane & 15);

  auto stageB = [&](int nb, int kt) {
#pragma unroll
    for (int r = 0; r < 4; ++r) {
      const int cbase = r * 512 + wv * 64;   // wave-uniform base
      const int c = cbase + lane;            // 0..2047 16B chunks
      const int row = c >> 2;
      const int swcol = ((c & 3) ^ ((row >> 1) & 3)) * 8;  // source pre-swizzle
      gload16(Bg + (size_t)row * cL + kt + swcol, &Bs[nb][cbase * 8]);
    }
  };
  auto transform = [&](int ck, float4 v) -> short4v {
    float* dst = sp + ck * 32;
    const float p0 = __expf(v.x - m) * invl;
    const float p1 = __expf(v.y - m) * invl;
    const float p2 = __expf(v.z - m) * invl;
    const float p3 = __expf(v.w - m) * invl;
    *(float4*)dst = make_float4(p0, p1, p2, p3);
    short4v pb = { f2bf(p0), f2bf(p1), f2bf(p2), f2bf(p3) };
    return pb;
  };

  // ---- prologue: DMA tile 0; transform chunk 0 -> Pb[0] ----
  stageB(0, 0);
  float4 c = *(const float4*)(sp);
  short4v pb = transform(0, c);
  c = *(const float4*)(sp + 32);
  *(short4v*)&Pb[0][pidx] = pb;

  for (int k = 0; k < 63; ++k) {
    const int cb = k & 1, nb = cb ^ 1;
    // s1: transform chunk k+1 (VALU + 1 attn store), prefetch chunk (k+2)&63
    pb = transform(k + 1, c);
    const int kc = (k + 2) & 63;   // k=62 wraps to chunk 0: dead load, keeps count
    c = *(const float4*)(sp + kc * 32);
    // s2: tile-k DMA done (2 newest vm ops = this iter's store + load);
    //     my ds ops drained for barrier visibility
    asm volatile("s_waitcnt vmcnt(2) lgkmcnt(0)" ::: "memory");
    __builtin_amdgcn_sched_barrier(0);
    // s3: the ONLY barrier per tile (no vmcnt(0) drain)
    __builtin_amdgcn_s_barrier();
    __builtin_amdgcn_sched_barrier(0);
    // s4: publish P tile k+1 (readers are behind next barrier)
    *(short4v*)&Pb[nb][pidx] = pb;
    // s5: DMA tile k+1 (WAR-safe: all tile-k-1 readers passed this barrier)
    stageB(nb, (k + 1) * 32);
    __builtin_amdgcn_sched_barrier(0);  // pin DMA before compute: vmcnt(2) has 0 slack
    // s6: compute tile k
    bf16x8 af[4], bfv[4];
#pragma unroll
    for (int i = 0; i < 4; ++i) {
      const int rA = arr + i * 16;
      af[i] = *(const bf16x8*)&Pb[cb][rA * 32 + ((qk ^ ((rA >> 1) & 3)) << 3)];
    }
#pragma unroll
    for (int j = 0; j < 4; ++j) {
      const int rB = br + j * 16;
      bfv[j] = *(const bf16x8*)&Bs[cb][rB * 32 + ((qk ^ ((rB >> 1) & 3)) << 3)];
    }
    __builtin_amdgcn_s_setprio(1);
#pragma unroll
    for (int i = 0; i < 4; ++i)
#pragma unroll
      for (int j = 0; j < 4; ++j)
        acc[i][j] = __builtin_amdgcn_mfma_f32_16x16x32_bf16(af[i], bfv[j], acc[i][j], 0, 0, 0);
    __builtin_amdgcn_s_setprio(0);
  }

  // ---- peeled tile 63 (buffers 1) ----
  asm volatile("s_waitcnt vmcnt(0) lgkmcnt(0)" ::: "memory");
  __builtin_amdgcn_sched_barrier(0);
  __builtin_amdgcn_s_barrier();
  __builtin_amdgcn_sched_barrier(0);
  {
    bf16x8 af[4], bfv[4];
#pragma unroll
    for (int i = 0; i < 4; ++i) {
      const int rA = arr + i * 16;
      af[i] = *(const bf16x8*)&Pb[1][rA * 32 + ((qk ^ ((rA >> 1) & 3)) << 3)];
    }
#pragma unroll
    for (int j = 0; j < 4; ++j) {
      const int rB = br + j * 16;
      bfv[j] = *(const bf16x8*)&Bs[1][rB * 32 + ((qk ^ ((rB >> 1) & 3)) << 3)];
    }
    __builtin_amdgcn_s_setprio(1);
#pragma unroll
    for (int i = 0; i < 4; ++i)
#pragma unroll
      for (int j = 0; j < 4; ++j)
        acc[i][j] = __builtin_amdgcn_mfma_f32_16x16x32_bf16(af[i], bfv[j], acc[i][j], 0, 0, 0);
    __builtin_amdgcn_s_setprio(0);
  }

  // ---- epilogue -> comb permuted layout: j = (e>>6)*512 + h*64 + (e&63) ----
  const int r0 = (lane >> 4) * 4;
  const int cc = lane & 15;
  short* C = comb + (size_t)(z >> 3) * ((size_t)cL * (cH * cD));
  const int h = z & 7;
  const int rowbase = rowblk * 64 + r0;
#pragma unroll
  for (int i = 0; i < 4; ++i)
#pragma unroll
    for (int j = 0; j < 4; ++j) {
      const int e = wv * 64 + j * 16 + cc;
      const int jc = ((e >> 6) << 9) + (h << 6) + (e & 63);
#pragma unroll
      for (int r = 0; r < 4; ++r)
        C[(size_t)(rowbase + i * 16 + r) * (cH * cD) + jc] = f2bf(acc[i][j][r]);
    }
}

// --------------------- sum the four split-K partials ------------------------
__global__ __launch_bounds__(256) void add_quads(const float4* __restrict__ p,
                                                 float4* __restrict__ out) {
  const int i = blockIdx.x * 256 + threadIdx.x;
  constexpr int S = (cB * cL * cD) / 4;
  const float4 a = p[i], b = p[i + S], c = p[i + 2 * S], d = p[i + 3 * S];
  out[i] = make_float4(a.x + b.x + c.x + d.x, a.y + b.y + c.y + d.y,
                       a.z + b.z + c.z + d.z, a.w + b.w + c.w + d.w);
}

// --------------------------------- launch -----------------------------------
extern "C" void kernel_launch(void* const* d_in, const int* in_sizes, int n_in,
                              void* d_out, int out_size, void* d_ws, size_t ws_size,
                              hipStream_t stream) {
  (void)in_sizes; (void)n_in; (void)out_size;

  const float* q  = (const float*)d_in[0];
  const float* k  = (const float*)d_in[1];
  const float* v  = (const float*)d_in[2];
  const float* Wq = (const float*)d_in[3];
  const float* Wk = (const float*)d_in[4];
  const float* Wv = (const float*)d_in[5];
  const float* Wo = (const float*)d_in[6];

  float* out  = (float*)d_out;
  float* attn = out + (size_t)cB * cL * cD;  // 2,097,152 floats in

  constexpr size_t Mi = 1ull << 20;
  char* ws = (char*)d_ws;
  short* qbf = (short*)(ws + 0 * Mi);
  short* kbf = (short*)(ws + 4 * Mi);
  short* vbf = (short*)(ws + 8 * Mi);
  short* wqb = (short*)(ws + 12 * Mi);
  short* wkb = (short*)(ws + 16 * Mi);
  short* wvb = (short*)(ws + 20 * Mi);
  short* wob = (short*)(ws + 24 * Mi);
  short* qh  = (short*)(ws + 28 * Mi);   // 32 MiB; dead after scores
  short* kh  = (short*)(ws + 60 * Mi);   // 32 MiB; dead after scores
  short* vhT = (short*)(ws + 92 * Mi);   // 32 MiB
  short* comb = qh;                      // alias: written after qh dead
  float2* stats  = (float2*)(ws + 0 * Mi);  // alias qbf (dead after projections)
  float2* pstats = (float2*)(ws + 4 * Mi);  // 8 MiB, alias kbf+vbf (dead after proj)
  float*  pout   = (float*)(ws + 60 * Mi);  // alias kh (dead after scores), 32 MiB

  if (ws_size < 124 * Mi) {
    fprintf(stderr, "kernel_launch: ws too small (%zu < %zu)\n", ws_size, 124 * Mi);
    return;
  }

  // 1) convert inputs/weights to bf16 (7 same-size tensors, one launch)
  CvtArgs ca;
  ca.s[0] = (const float4*)q;  ca.d[0] = (short4v*)qbf;
  ca.s[1] = (const float4*)k;  ca.d[1] = (short4v*)kbf;
  ca.s[2] = (const float4*)v;  ca.d[2] = (short4v*)vbf;
  ca.s[3] = (const float4*)Wq; ca.d[3] = (short4v*)wqb;
  ca.s[4] = (const float4*)Wk; ca.d[4] = (short4v*)wkb;
  ca.s[5] = (const float4*)Wv; ca.d[5] = (short4v*)wvb;
  ca.s[6] = (const float4*)Wo; ca.d[6] = (short4v*)wob;
  cvt_all<<<dim3(2048, 7), 256, 0, stream>>>(ca);

  // 2) per-head projections (z = b*8+h), M=2048 N=512 K=512
  gemm_nt<M_PROJ ><<<dim3(4, 16, 16), 256, 0, stream>>>(qbf, wqb, qh, nullptr);
  gemm_nt<M_PROJ ><<<dim3(4, 16, 16), 256, 0, stream>>>(kbf, wkb, kh, nullptr);
  gemm_nt<M_PROJV><<<dim3(4, 16, 16), 256, 0, stream>>>(vbf, wvb, vhT, nullptr);

  // 3) scores -> d_out attn region (fp32, scaled) + per-block row stats partials
  gemm_nt<M_SCORES><<<dim3(16, 16, 16), 256, 0, stream>>>(qh, kh, attn, pstats);

  // 4) combine partials -> (m, 1/l) per row
  combine_stats<<<cB * cH * cL / 256, 256, 0, stream>>>(pstats, stats);

  // 5) fused: normalize attn in place + ctx -> comb (pipelined, 2 blocks/CU)
  fused_ctx<<<dim3(32, cB * cH), 512, 0, stream>>>(vhT, stats, attn, comb);

  // 6) out = comb @ Wo^T, split-K x4 (z = b*4 + kq) -> fp32 partials
  gemm_nt<M_OUT><<<dim3(4, 16, 8), 256, 0, stream>>>(comb, wob, (void*)pout, nullptr);

  // 7) out = sum of 4 partials
  add_quads<<<2048, 256, 0, stream>>>((const float4*)pout, (float4*)out);
}

// Round 5
// 709.618 us; speedup vs baseline: 1.1677x; 1.0435x over previous
//
#include <hip/hip_runtime.h>
#include <cstdio>
#include <cstdint>

// ---------------------------------------------------------------------------
// MultiHeadSelfAttention (B=2, L=2048, D=512, H=8), per-head full-DxD projs.
// R8 = R7 with compile fix: add_quads nontemporal loads via ext_vector f32x4
//      (clang rejects HIP_vector_type float4* for nontemporal builtins).
// R7 = R6 + (a) raw scores stored FP16 in the upper half of each attn row's
//      fp32 slot (halves score write + fused read; stats stay exact fp32);
//      (b) combine_stats folded into fused_ctx prologue (launch removed);
//      (c) nontemporal loads/stores on all streaming S/attn traffic.
// R6/R5: fused_ctx 64-row blocks 2/CU; tri-buffered counted-vmcnt gemm;
//      split-K x4 out-GEMM.  In-place clobber proof: fp32 chunk j write
//      clobbers fp16 tiles 2j-64/2j-63 <= j, consumed >=1 tile earlier.
// ---------------------------------------------------------------------------

#define AS1 __attribute__((address_space(1)))
#define AS3 __attribute__((address_space(3)))

typedef __attribute__((ext_vector_type(8))) short bf16x8;   // 8 bf16 = 4 VGPRs
typedef __attribute__((ext_vector_type(4))) short short4v;  // 4 bf16 = 8 B
typedef __attribute__((ext_vector_type(4))) float f32x4;    // MFMA acc
typedef __attribute__((ext_vector_type(4))) _Float16 h4;    // 4 fp16 = 8 B

constexpr int cB = 2, cH = 8, cL = 2048, cD = 512;
constexpr float SCORE_SCALE = 0.044194173824159216f; // 1/sqrt(512)

__device__ __forceinline__ short f2bf(float f) {
  return __builtin_bit_cast(short, static_cast<__bf16>(f)); // RNE convert
}

__device__ __forceinline__ void gload16(const void* g, void* l) {
  // async global->LDS, 16B per lane; LDS dest is wave-uniform base + lane*16
  __builtin_amdgcn_global_load_lds((AS1 const void*)g, (AS3 void*)l, 16, 0, 0);
}

// --------------------------- fp32 -> bf16 convert (merged) ------------------
struct CvtArgs { const float4* s[7]; short4v* d[7]; };

__global__ __launch_bounds__(256) void cvt_all(CvtArgs a) {
  const int z = blockIdx.y;
  const int i = blockIdx.x * 256 + threadIdx.x;
  const float4 v = a.s[z][i];
  short4v o = { f2bf(v.x), f2bf(v.y), f2bf(v.z), f2bf(v.w) };
  a.d[z][i] = o;
}

// ------------------------------- GEMM modes ---------------------------------
enum { M_PROJ = 0, M_PROJV = 1, M_SCORES = 2, M_OUT = 3 };

template <int MODE>
__global__ __launch_bounds__(256) void gemm_nt(const short* __restrict__ Ap,
                                               const short* __restrict__ Bp,
                                               void* __restrict__ Cp,
                                               float2* __restrict__ Sp) {
  constexpr int K   = (MODE == M_OUT) ? 1024 : 512;   // k-loop extent
  constexpr int LDA = (MODE == M_OUT) ? 4096 : 512;   // A row stride
  constexpr int LDB = (MODE == M_OUT) ? 4096 : 512;   // B row stride

  __shared__ short As[3][128 * 32];  // 24 KB (tri-buffer)
  __shared__ short Bs[3][128 * 32];  // 24 KB

  const int t = threadIdx.x;
  const int lane = t & 63;
  const int wv = t >> 6;          // wave 0..3
  const int wm = wv >> 1, wn = wv & 1;
  const int z = blockIdx.z;

  size_t Aoff, Boff;
  if constexpr (MODE == M_PROJ || MODE == M_PROJV) {
    Aoff = (size_t)(z >> 3) * ((size_t)cL * cD);   // per-b input
    Boff = (size_t)(z & 7) * ((size_t)cD * cD);    // per-h weight
  } else if constexpr (MODE == M_SCORES) {
    Aoff = (size_t)z * ((size_t)cL * cD);          // qh[b,h]
    Boff = (size_t)z * ((size_t)cL * cD);          // kh[b,h]
  } else {                                         // M_OUT split-K x4: z = b*4+kq
    Aoff = (size_t)(z >> 2) * ((size_t)cL * 4096) + (size_t)(z & 3) * 1024;
    Boff = (size_t)(z & 3) * 1024;
  }

  const short* Ag0 = Ap + Aoff + (size_t)(blockIdx.y * 128) * LDA;
  const short* Bg0 = Bp + Boff + (size_t)(blockIdx.x * 128) * LDB;

  f32x4 acc[4][4];
#pragma unroll
  for (int i = 0; i < 4; ++i)
#pragma unroll
    for (int j = 0; j < 4; ++j) acc[i][j] = (f32x4){0.f, 0.f, 0.f, 0.f};

  auto stage = [&](int b, int kt) {
#pragma unroll
    for (int r = 0; r < 2; ++r) {
      const int cbase = r * 256 + wv * 64;    // wave-uniform chunk base
      const int c = cbase + lane;             // 0..511 16B chunks
      const int row = c >> 2, col = (c & 3) * 8;
      gload16(Ag0 + (size_t)row * LDA + kt + col, &As[b][cbase * 8]);
    }
#pragma unroll
    for (int r = 0; r < 2; ++r) {
      const int cbase = r * 256 + wv * 64;
      const int c = cbase + lane;
      const int row = c >> 2, col = (c & 3) * 8;
      gload16(Bg0 + (size_t)row * LDB + kt + col, &Bs[b][cbase * 8]);
    }
  };

  const int koff = (lane >> 4) * 8;           // A/B frag: k = quad*8 + j
  const int ar = wm * 64 + (lane & 15);
  const int br = wn * 64 + (lane & 15);

  constexpr int nt = K / 32;
  stage(0, 0);
  stage(1, 32);
  int cur = 0, pre = 2;
  for (int tt = 0; tt < nt; ++tt) {
    // counted wait: leaves only the newest stage (tt+1) in flight; in-order
    // retirement => stage(tt) complete. Last iter: full drain.
    if (tt < nt - 1) { asm volatile("s_waitcnt vmcnt(4) lgkmcnt(0)" ::: "memory"); }
    else             { asm volatile("s_waitcnt vmcnt(0) lgkmcnt(0)" ::: "memory"); }
    __builtin_amdgcn_sched_barrier(0);
    __builtin_amdgcn_s_barrier();
    __builtin_amdgcn_sched_barrier(0);
    if (tt + 2 < nt) stage(pre, (tt + 2) * 32);  // post-barrier: WAR-safe
    __builtin_amdgcn_sched_barrier(0);

    bf16x8 af[4], bfv[4];
#pragma unroll
    for (int i = 0; i < 4; ++i) af[i] = *(const bf16x8*)&As[cur][(ar + i * 16) * 32 + koff];
#pragma unroll
    for (int j = 0; j < 4; ++j) bfv[j] = *(const bf16x8*)&Bs[cur][(br + j * 16) * 32 + koff];
    __builtin_amdgcn_s_setprio(1);
#pragma unroll
    for (int i = 0; i < 4; ++i)
#pragma unroll
      for (int j = 0; j < 4; ++j)
        acc[i][j] = __builtin_amdgcn_mfma_f32_16x16x32_bf16(af[i], bfv[j], acc[i][j], 0, 0, 0);
    __builtin_amdgcn_s_setprio(0);
    cur = (cur == 2) ? 0 : cur + 1;
    pre = (pre == 2) ? 0 : pre + 1;
  }

  // ---- epilogue: C/D layout col=lane&15, row=(lane>>4)*4+reg ----
  const int r0 = (lane >> 4) * 4;
  const int cc = lane & 15;
  const int rowbase = blockIdx.y * 128 + wm * 64 + r0;
  const int colbase = blockIdx.x * 128 + wn * 64 + cc;

  if constexpr (MODE == M_PROJ) {
    short* C = (short*)Cp + (size_t)z * ((size_t)cL * cD);
#pragma unroll
    for (int i = 0; i < 4; ++i)
#pragma unroll
      for (int j = 0; j < 4; ++j)
#pragma unroll
        for (int r = 0; r < 4; ++r)
          C[(size_t)(rowbase + i * 16 + r) * cD + (colbase + j * 16)] = f2bf(acc[i][j][r]);
  } else if constexpr (MODE == M_PROJV) {
    // store transposed: vhT[e][l]
    short* C = (short*)Cp + (size_t)z * ((size_t)cD * cL);
#pragma unroll
    for (int i = 0; i < 4; ++i)
#pragma unroll
      for (int j = 0; j < 4; ++j) {
        short4v o = { f2bf(acc[i][j][0]), f2bf(acc[i][j][1]),
                      f2bf(acc[i][j][2]), f2bf(acc[i][j][3]) };
        *(short4v*)&C[(size_t)(colbase + j * 16) * cL + (rowbase + i * 16)] = o;
      }
  } else if constexpr (MODE == M_SCORES) {
    // fp16 scores -> upper 4KB of each attn row's 8KB fp32 slot (+4096)
    char* Cb = (char*)Cp + ((size_t)z << 24);   // z * 16 MiB
    float2* ps = Sp + (size_t)z * ((size_t)cL * 32);
    const int pid = blockIdx.x * 2 + wn;  // 0..31: which 64-col slice
#pragma unroll
    for (int i = 0; i < 4; ++i) {
      float sv[4][4];
#pragma unroll
      for (int j = 0; j < 4; ++j)
#pragma unroll
        for (int r = 0; r < 4; ++r) sv[j][r] = acc[i][j][r] * SCORE_SCALE;
#pragma unroll
      for (int j = 0; j < 4; ++j)
#pragma unroll
        for (int r = 0; r < 4; ++r) {
          const _Float16 hv = (_Float16)sv[j][r];
          __builtin_nontemporal_store(
              __builtin_bit_cast(short, hv),
              (short*)(Cb + (size_t)(rowbase + i * 16 + r) * 8192 + 4096 +
                       (size_t)(colbase + j * 16) * 2));
        }
      // per-row partial (max, sum-exp) over this wave's 64 cols (exact fp32)
#pragma unroll
      for (int r = 0; r < 4; ++r) {
        float mx = fmaxf(fmaxf(sv[0][r], sv[1][r]), fmaxf(sv[2][r], sv[3][r]));
#pragma unroll
        for (int off = 1; off < 16; off <<= 1) mx = fmaxf(mx, __shfl_xor(mx, off, 64));
        float sm = __expf(sv[0][r] - mx) + __expf(sv[1][r] - mx) +
                   __expf(sv[2][r] - mx) + __expf(sv[3][r] - mx);
#pragma unroll
        for (int off = 1; off < 16; off <<= 1) sm += __shfl_xor(sm, off, 64);
        if ((lane & 15) == 0)
          ps[(size_t)(rowbase + i * 16 + r) * 32 + pid] = make_float2(mx, sm);
      }
    }
  } else {  // M_OUT: fp32 partial (kq) into ws
    float* C = (float*)Cp + (size_t)((z & 3) * 2 + (z >> 2)) * ((size_t)cL * cD);
#pragma unroll
    for (int i = 0; i < 4; ++i)
#pragma unroll
      for (int j = 0; j < 4; ++j)
#pragma unroll
        for (int r = 0; r < 4; ++r)
          C[(size_t)(rowbase + i * 16 + r) * cD + (colbase + j * 16)] = acc[i][j][r];
  }
}

// ---------------- fused softmax-normalize + ctx (fp16 S in place) -----------
// grid (rowblk=32, z=16) = 512 blocks = 2 blocks/CU. 512 threads = 8 N-waves,
// block tile 64 rows x 512 e. Pipelined: dbuf Bs/Pb, DMA one tile ahead, ONE
// s_barrier/tile with counted vmcnt(2). Prologue folds combine_stats
// (8 threads/row x 4 partials + shfl_xor over 8-lane group).
__global__ __launch_bounds__(512, 4) void fused_ctx(const short* __restrict__ vhT,
                                                    const float2* __restrict__ pstats,
                                                    float* __restrict__ attn,
                                                    short* __restrict__ comb) {
  __shared__ short Bs[2][512 * 32];  // 64 KB vhT tiles (dbuf), swizzled
  __shared__ short Pb[2][64 * 32];   //  8 KB P bf16 (dbuf), swizzled

  const int t = threadIdx.x;
  const int lane = t & 63;
  const int wv = t >> 6;          // 0..7 (N-wave)
  const int rowblk = blockIdx.x;  // 0..31
  const int z = blockIdx.y;       // b*8+h

  // transform-thread coords: thread owns (row = t>>3, 4-col chunk t&7 per tile)
  const int trow = t >> 3;                       // 0..63
  const int tcb = t & 7;                         // which 4-col piece in 32-tile
  const int pidx = trow * 32 + (((tcb >> 1) ^ ((trow >> 1) & 3)) << 3) + ((tcb & 1) << 2);
  const int grow = rowblk * 64 + trow;

  // ---- folded combine_stats: (m, 1/l) from 32 partials, 8 threads/row ----
  const float2* pp = pstats + ((size_t)z * cL + grow) * 32 + tcb * 4;
  const float2 q0 = pp[0], q1 = pp[1], q2 = pp[2], q3 = pp[3];
  float m = fmaxf(fmaxf(q0.x, q1.x), fmaxf(q2.x, q3.x));
#pragma unroll
  for (int off = 1; off < 8; off <<= 1) m = fmaxf(m, __shfl_xor(m, off, 64));
  float l = q0.y * __expf(q0.x - m) + q1.y * __expf(q1.x - m) +
            q2.y * __expf(q2.x - m) + q3.y * __expf(q3.x - m);
#pragma unroll
  for (int off = 1; off < 8; off <<= 1) l += __shfl_xor(l, off, 64);
  const float invl = 1.0f / l;

  char* rowb = (char*)attn + ((size_t)z << 24) + (size_t)grow * 8192;
  float* spf = (float*)rowb + tcb * 4;          // fp32 attn out (lower 8KB slot)
  const h4* sph = (const h4*)(rowb + 4096);     // fp16 S (upper 4KB); idx tcb+k*8

  const short* Bg = vhT + (size_t)z * ((size_t)cD * cL);

  f32x4 acc[4][4];
#pragma unroll
  for (int i = 0; i < 4; ++i)
#pragma unroll
    for (int j = 0; j < 4; ++j) acc[i][j] = (f32x4){0.f, 0.f, 0.f, 0.f};

  const int qk = lane >> 4;                  // frag k-chunk 0..3
  const int arr = lane & 15;
  const int br = wv * 64 + (lane & 15);

  auto stageB = [&](int nb, int kt) {
#pragma unroll
    for (int r = 0; r < 4; ++r) {
      const int cbase = r * 512 + wv * 64;   // wave-uniform base
      const int c = cbase + lane;            // 0..2047 16B chunks
      const int row = c >> 2;
      const int swcol = ((c & 3) ^ ((row >> 1) & 3)) * 8;  // source pre-swizzle
      gload16(Bg + (size_t)row * cL + kt + swcol, &Bs[nb][cbase * 8]);
    }
  };
  auto transform = [&](int ck, h4 hv) -> short4v {
    const float p0 = __expf((float)hv[0] - m) * invl;
    const float p1 = __expf((float)hv[1] - m) * invl;
    const float p2 = __expf((float)hv[2] - m) * invl;
    const float p3 = __expf((float)hv[3] - m) * invl;
    __builtin_nontemporal_store((f32x4){p0, p1, p2, p3}, (f32x4*)(spf + ck * 32));
    short4v pb = { f2bf(p0), f2bf(p1), f2bf(p2), f2bf(p3) };
    return pb;
  };

  // ---- prologue: DMA tile 0; transform chunk 0 -> Pb[0] ----
  stageB(0, 0);
  h4 hc = __builtin_nontemporal_load(sph + tcb);        // tile 0
  short4v pb = transform(0, hc);
  hc = __builtin_nontemporal_load(sph + tcb + 8);       // tile 1
  *(short4v*)&Pb[0][pidx] = pb;

  for (int k = 0; k < 63; ++k) {
    const int cb = k & 1, nb = cb ^ 1;
    // s1: transform chunk k+1 (VALU + 1 attn store), prefetch chunk (k+2)&63
    pb = transform(k + 1, hc);
    const int kc = (k + 2) & 63;   // k=62 wraps to chunk 0: dead load, keeps count
    hc = __builtin_nontemporal_load(sph + tcb + kc * 8);
    // s2: tile-k DMA done (2 newest vm ops = this iter's store + load);
    //     my ds ops drained for barrier visibility
    asm volatile("s_waitcnt vmcnt(2) lgkmcnt(0)" ::: "memory");
    __builtin_amdgcn_sched_barrier(0);
    // s3: the ONLY barrier per tile (no vmcnt(0) drain)
    __builtin_amdgcn_s_barrier();
    __builtin_amdgcn_sched_barrier(0);
    // s4: publish P tile k+1 (readers are behind next barrier)
    *(short4v*)&Pb[nb][pidx] = pb;
    // s5: DMA tile k+1 (WAR-safe: all tile-k-1 readers passed this barrier)
    stageB(nb, (k + 1) * 32);
    __builtin_amdgcn_sched_barrier(0);  // pin DMA before compute: vmcnt(2) has 0 slack
    // s6: compute tile k
    bf16x8 af[4], bfv[4];
#pragma unroll
    for (int i = 0; i < 4; ++i) {
      const int rA = arr + i * 16;
      af[i] = *(const bf16x8*)&Pb[cb][rA * 32 + ((qk ^ ((rA >> 1) & 3)) << 3)];
    }
#pragma unroll
    for (int j = 0; j < 4; ++j) {
      const int rB = br + j * 16;
      bfv[j] = *(const bf16x8*)&Bs[cb][rB * 32 + ((qk ^ ((rB >> 1) & 3)) << 3)];
    }
    __builtin_amdgcn_s_setprio(1);
#pragma unroll
    for (int i = 0; i < 4; ++i)
#pragma unroll
      for (int j = 0; j < 4; ++j)
        acc[i][j] = __builtin_amdgcn_mfma_f32_16x16x32_bf16(af[i], bfv[j], acc[i][j], 0, 0, 0);
    __builtin_amdgcn_s_setprio(0);
  }

  // ---- peeled tile 63 (buffers 1) ----
  asm volatile("s_waitcnt vmcnt(0) lgkmcnt(0)" ::: "memory");
  __builtin_amdgcn_sched_barrier(0);
  __builtin_amdgcn_s_barrier();
  __builtin_amdgcn_sched_barrier(0);
  {
    bf16x8 af[4], bfv[4];
#pragma unroll
    for (int i = 0; i < 4; ++i) {
      const int rA = arr + i * 16;
      af[i] = *(const bf16x8*)&Pb[1][rA * 32 + ((qk ^ ((rA >> 1) & 3)) << 3)];
    }
#pragma unroll
    for (int j = 0; j < 4; ++j) {
      const int rB = br + j * 16;
      bfv[j] = *(const bf16x8*)&Bs[1][rB * 32 + ((qk ^ ((rB >> 1) & 3)) << 3)];
    }
    __builtin_amdgcn_s_setprio(1);
#pragma unroll
    for (int i = 0; i < 4; ++i)
#pragma unroll
      for (int j = 0; j < 4; ++j)
        acc[i][j] = __builtin_amdgcn_mfma_f32_16x16x32_bf16(af[i], bfv[j], acc[i][j], 0, 0, 0);
    __builtin_amdgcn_s_setprio(0);
  }

  // ---- epilogue -> comb permuted layout: j = (e>>6)*512 + h*64 + (e&63) ----
  const int r0 = (lane >> 4) * 4;
  const int cc = lane & 15;
  short* C = comb + (size_t)(z >> 3) * ((size_t)cL * (cH * cD));
  const int h = z & 7;
  const int rowbase = rowblk * 64 + r0;
#pragma unroll
  for (int i = 0; i < 4; ++i)
#pragma unroll
    for (int j = 0; j < 4; ++j) {
      const int e = wv * 64 + j * 16 + cc;
      const int jc = ((e >> 6) << 9) + (h << 6) + (e & 63);
#pragma unroll
      for (int r = 0; r < 4; ++r)
        C[(size_t)(rowbase + i * 16 + r) * (cH * cD) + jc] = f2bf(acc[i][j][r]);
    }
}

// --------------------- sum the four split-K partials ------------------------
__global__ __launch_bounds__(256) void add_quads(const float* __restrict__ p,
                                                 float* __restrict__ out) {
  const int i = blockIdx.x * 256 + threadIdx.x;
  constexpr int S = cB * cL * cD;  // floats per partial
  const f32x4 a = __builtin_nontemporal_load((const f32x4*)p + i);
  const f32x4 b = __builtin_nontemporal_load((const f32x4*)(p + S) + i);
  const f32x4 c = __builtin_nontemporal_load((const f32x4*)(p + 2 * S) + i);
  const f32x4 d = __builtin_nontemporal_load((const f32x4*)(p + 3 * S) + i);
  const f32x4 s = a + b + c + d;
  *((f32x4*)out + i) = s;
}

// --------------------------------- launch -----------------------------------
extern "C" void kernel_launch(void* const* d_in, const int* in_sizes, int n_in,
                              void* d_out, int out_size, void* d_ws, size_t ws_size,
                              hipStream_t stream) {
  (void)in_sizes; (void)n_in; (void)out_size;

  const float* q  = (const float*)d_in[0];
  const float* k  = (const float*)d_in[1];
  const float* v  = (const float*)d_in[2];
  const float* Wq = (const float*)d_in[3];
  const float* Wk = (const float*)d_in[4];
  const float* Wv = (const float*)d_in[5];
  const float* Wo = (const float*)d_in[6];

  float* out  = (float*)d_out;
  float* attn = out + (size_t)cB * cL * cD;  // 2,097,152 floats in

  constexpr size_t Mi = 1ull << 20;
  char* ws = (char*)d_ws;
  short* qbf = (short*)(ws + 0 * Mi);
  short* kbf = (short*)(ws + 4 * Mi);
  short* vbf = (short*)(ws + 8 * Mi);
  short* wqb = (short*)(ws + 12 * Mi);
  short* wkb = (short*)(ws + 16 * Mi);
  short* wvb = (short*)(ws + 20 * Mi);
  short* wob = (short*)(ws + 24 * Mi);
  short* qh  = (short*)(ws + 28 * Mi);   // 32 MiB; dead after scores
  short* kh  = (short*)(ws + 60 * Mi);   // 32 MiB; dead after scores
  short* vhT = (short*)(ws + 92 * Mi);   // 32 MiB
  short* comb = qh;                      // alias: written after qh dead
  float2* pstats = (float2*)(ws + 4 * Mi);  // 8 MiB, alias kbf+vbf (dead after proj)
  float*  pout   = (float*)(ws + 60 * Mi);  // alias kh (dead after scores), 32 MiB

  if (ws_size < 124 * Mi) {
    fprintf(stderr, "kernel_launch: ws too small (%zu < %zu)\n", ws_size, 124 * Mi);
    return;
  }

  // 1) convert inputs/weights to bf16 (7 same-size tensors, one launch)
  CvtArgs ca;
  ca.s[0] = (const float4*)q;  ca.d[0] = (short4v*)qbf;
  ca.s[1] = (const float4*)k;  ca.d[1] = (short4v*)kbf;
  ca.s[2] = (const float4*)v;  ca.d[2] = (short4v*)vbf;
  ca.s[3] = (const float4*)Wq; ca.d[3] = (short4v*)wqb;
  ca.s[4] = (const float4*)Wk; ca.d[4] = (short4v*)wkb;
  ca.s[5] = (const float4*)Wv; ca.d[5] = (short4v*)wvb;
  ca.s[6] = (const float4*)Wo; ca.d[6] = (short4v*)wob;
  cvt_all<<<dim3(2048, 7), 256, 0, stream>>>(ca);

  // 2) per-head projections (z = b*8+h), M=2048 N=512 K=512
  gemm_nt<M_PROJ ><<<dim3(4, 16, 16), 256, 0, stream>>>(qbf, wqb, qh, nullptr);
  gemm_nt<M_PROJ ><<<dim3(4, 16, 16), 256, 0, stream>>>(kbf, wkb, kh, nullptr);
  gemm_nt<M_PROJV><<<dim3(4, 16, 16), 256, 0, stream>>>(vbf, wvb, vhT, nullptr);

  // 3) scores -> fp16 in attn region upper-row-halves + row-stats partials
  gemm_nt<M_SCORES><<<dim3(16, 16, 16), 256, 0, stream>>>(qh, kh, attn, pstats);

  // 4) fused: stats-combine + normalize (fp16 S -> fp32 attn in place) + ctx
  fused_ctx<<<dim3(32, cB * cH), 512, 0, stream>>>(vhT, pstats, attn, comb);

  // 5) out = comb @ Wo^T, split-K x4 (z = b*4 + kq) -> fp32 partials
  gemm_nt<M_OUT><<<dim3(4, 16, 8), 256, 0, stream>>>(comb, wob, (void*)pout, nullptr);

  // 6) out = sum of 4 partials
  add_quads<<<2048, 256, 0, stream>>>(pout, out);
}

// Round 6
// 677.438 us; speedup vs baseline: 1.2231x; 1.0475x over previous
//
#include <hip/hip_runtime.h>
#include <cstdio>
#include <cstdint>

// ---------------------------------------------------------------------------
// MultiHeadSelfAttention (B=2, L=2048, D=512, H=8), per-head full-DxD projs.
// R9 = R8 + (a) nt REMOVED from S fp16 stores/loads so S (134 MB) stays
//      L3-resident between scores and fused (nt stays on attn fp32 output
//      stores only); (b) XCD-aware z-grouping block swizzle on fused_ctx and
//      all gemm grids (XCD x owns z in {x*ZPX..}) so per-z panels (vhT 2MB,
//      qh/kh 4MB, weights) live in ONE XCD's L2 instead of 8 copies.
// R8/R7: fp16 S packed in attn-row upper halves; stats folded; counted-vmcnt
//      pipelines everywhere; split-K x4 out-GEMM.
// ---------------------------------------------------------------------------

#define AS1 __attribute__((address_space(1)))
#define AS3 __attribute__((address_space(3)))

typedef __attribute__((ext_vector_type(8))) short bf16x8;   // 8 bf16 = 4 VGPRs
typedef __attribute__((ext_vector_type(4))) short short4v;  // 4 bf16 = 8 B
typedef __attribute__((ext_vector_type(4))) float f32x4;    // MFMA acc
typedef __attribute__((ext_vector_type(4))) _Float16 h4;    // 4 fp16 = 8 B

constexpr int cB = 2, cH = 8, cL = 2048, cD = 512;
constexpr float SCORE_SCALE = 0.044194173824159216f; // 1/sqrt(512)

__device__ __forceinline__ short f2bf(float f) {
  return __builtin_bit_cast(short, static_cast<__bf16>(f)); // RNE convert
}

__device__ __forceinline__ void gload16(const void* g, void* l) {
  // async global->LDS, 16B per lane; LDS dest is wave-uniform base + lane*16
  __builtin_amdgcn_global_load_lds((AS1 const void*)g, (AS3 void*)l, 16, 0, 0);
}

// --------------------------- fp32 -> bf16 convert (merged) ------------------
struct CvtArgs { const float4* s[7]; short4v* d[7]; };

__global__ __launch_bounds__(256) void cvt_all(CvtArgs a) {
  const int z = blockIdx.y;
  const int i = blockIdx.x * 256 + threadIdx.x;
  const float4 v = a.s[z][i];
  short4v o = { f2bf(v.x), f2bf(v.y), f2bf(v.z), f2bf(v.w) };
  a.d[z][i] = o;
}

// ------------------------------- GEMM modes ---------------------------------
enum { M_PROJ = 0, M_PROJV = 1, M_SCORES = 2, M_OUT = 3 };

template <int MODE>
__global__ __launch_bounds__(256) void gemm_nt(const short* __restrict__ Ap,
                                               const short* __restrict__ Bp,
                                               void* __restrict__ Cp,
                                               float2* __restrict__ Sp) {
  constexpr int K   = (MODE == M_OUT) ? 1024 : 512;   // k-loop extent
  constexpr int LDA = (MODE == M_OUT) ? 4096 : 512;   // A row stride
  constexpr int LDB = (MODE == M_OUT) ? 4096 : 512;   // B row stride

  // ---- XCD-aware z-grouping decode: XCD x owns z in [x*ZPX, (x+1)*ZPX) ----
  constexpr int GX  = (MODE == M_SCORES) ? 16 : 4;
  constexpr int GY  = 16;
  constexpr int GZ  = (MODE == M_OUT) ? 8 : 16;
  constexpr int ZPX = GZ / 8;
  constexpr int GXY = GX * GY;
  const int li = (int)blockIdx.z * GXY + (int)blockIdx.y * GX + (int)blockIdx.x;
  const int sfl = li >> 3;
  const int bz = (li & 7) * ZPX + sfl / GXY;
  const int rem = sfl % GXY;
  const int by = rem / GX, bx = rem % GX;

  __shared__ short As[3][128 * 32];  // 24 KB (tri-buffer)
  __shared__ short Bs[3][128 * 32];  // 24 KB

  const int t = threadIdx.x;
  const int lane = t & 63;
  const int wv = t >> 6;          // wave 0..3
  const int wm = wv >> 1, wn = wv & 1;

  size_t Aoff, Boff;
  if constexpr (MODE == M_PROJ || MODE == M_PROJV) {
    Aoff = (size_t)(bz >> 3) * ((size_t)cL * cD);   // per-b input
    Boff = (size_t)(bz & 7) * ((size_t)cD * cD);    // per-h weight
  } else if constexpr (MODE == M_SCORES) {
    Aoff = (size_t)bz * ((size_t)cL * cD);          // qh[b,h]
    Boff = (size_t)bz * ((size_t)cL * cD);          // kh[b,h]
  } else {                                          // M_OUT split-K x4: z = b*4+kq
    Aoff = (size_t)(bz >> 2) * ((size_t)cL * 4096) + (size_t)(bz & 3) * 1024;
    Boff = (size_t)(bz & 3) * 1024;
  }

  const short* Ag0 = Ap + Aoff + (size_t)(by * 128) * LDA;
  const short* Bg0 = Bp + Boff + (size_t)(bx * 128) * LDB;

  f32x4 acc[4][4];
#pragma unroll
  for (int i = 0; i < 4; ++i)
#pragma unroll
    for (int j = 0; j < 4; ++j) acc[i][j] = (f32x4){0.f, 0.f, 0.f, 0.f};

  auto stage = [&](int b, int kt) {
#pragma unroll
    for (int r = 0; r < 2; ++r) {
      const int cbase = r * 256 + wv * 64;    // wave-uniform chunk base
      const int c = cbase + lane;             // 0..511 16B chunks
      const int row = c >> 2, col = (c & 3) * 8;
      gload16(Ag0 + (size_t)row * LDA + kt + col, &As[b][cbase * 8]);
    }
#pragma unroll
    for (int r = 0; r < 2; ++r) {
      const int cbase = r * 256 + wv * 64;
      const int c = cbase + lane;
      const int row = c >> 2, col = (c & 3) * 8;
      gload16(Bg0 + (size_t)row * LDB + kt + col, &Bs[b][cbase * 8]);
    }
  };

  const int koff = (lane >> 4) * 8;           // A/B frag: k = quad*8 + j
  const int ar = wm * 64 + (lane & 15);
  const int br = wn * 64 + (lane & 15);

  constexpr int nt = K / 32;
  stage(0, 0);
  stage(1, 32);
  int cur = 0, pre = 2;
  for (int tt = 0; tt < nt; ++tt) {
    // counted wait: leaves only the newest stage (tt+1) in flight; in-order
    // retirement => stage(tt) complete. Last iter: full drain.
    if (tt < nt - 1) { asm volatile("s_waitcnt vmcnt(4) lgkmcnt(0)" ::: "memory"); }
    else             { asm volatile("s_waitcnt vmcnt(0) lgkmcnt(0)" ::: "memory"); }
    __builtin_amdgcn_sched_barrier(0);
    __builtin_amdgcn_s_barrier();
    __builtin_amdgcn_sched_barrier(0);
    if (tt + 2 < nt) stage(pre, (tt + 2) * 32);  // post-barrier: WAR-safe
    __builtin_amdgcn_sched_barrier(0);

    bf16x8 af[4], bfv[4];
#pragma unroll
    for (int i = 0; i < 4; ++i) af[i] = *(const bf16x8*)&As[cur][(ar + i * 16) * 32 + koff];
#pragma unroll
    for (int j = 0; j < 4; ++j) bfv[j] = *(const bf16x8*)&Bs[cur][(br + j * 16) * 32 + koff];
    __builtin_amdgcn_s_setprio(1);
#pragma unroll
    for (int i = 0; i < 4; ++i)
#pragma unroll
      for (int j = 0; j < 4; ++j)
        acc[i][j] = __builtin_amdgcn_mfma_f32_16x16x32_bf16(af[i], bfv[j], acc[i][j], 0, 0, 0);
    __builtin_amdgcn_s_setprio(0);
    cur = (cur == 2) ? 0 : cur + 1;
    pre = (pre == 2) ? 0 : pre + 1;
  }

  // ---- epilogue: C/D layout col=lane&15, row=(lane>>4)*4+reg ----
  const int r0 = (lane >> 4) * 4;
  const int cc = lane & 15;
  const int rowbase = by * 128 + wm * 64 + r0;
  const int colbase = bx * 128 + wn * 64 + cc;

  if constexpr (MODE == M_PROJ) {
    short* C = (short*)Cp + (size_t)bz * ((size_t)cL * cD);
#pragma unroll
    for (int i = 0; i < 4; ++i)
#pragma unroll
      for (int j = 0; j < 4; ++j)
#pragma unroll
        for (int r = 0; r < 4; ++r)
          C[(size_t)(rowbase + i * 16 + r) * cD + (colbase + j * 16)] = f2bf(acc[i][j][r]);
  } else if constexpr (MODE == M_PROJV) {
    // store transposed: vhT[e][l]
    short* C = (short*)Cp + (size_t)bz * ((size_t)cD * cL);
#pragma unroll
    for (int i = 0; i < 4; ++i)
#pragma unroll
      for (int j = 0; j < 4; ++j) {
        short4v o = { f2bf(acc[i][j][0]), f2bf(acc[i][j][1]),
                      f2bf(acc[i][j][2]), f2bf(acc[i][j][3]) };
        *(short4v*)&C[(size_t)(colbase + j * 16) * cL + (rowbase + i * 16)] = o;
      }
  } else if constexpr (MODE == M_SCORES) {
    // fp16 scores -> upper 4KB of each attn row's 8KB fp32 slot (+4096).
    // PLAIN stores (no nt): 134 MB of S must stay L3-resident for fused_ctx.
    char* Cb = (char*)Cp + ((size_t)bz << 24);   // z * 16 MiB
    float2* ps = Sp + (size_t)bz * ((size_t)cL * 32);
    const int pid = bx * 2 + wn;  // 0..31: which 64-col slice
#pragma unroll
    for (int i = 0; i < 4; ++i) {
      float sv[4][4];
#pragma unroll
      for (int j = 0; j < 4; ++j)
#pragma unroll
        for (int r = 0; r < 4; ++r) sv[j][r] = acc[i][j][r] * SCORE_SCALE;
#pragma unroll
      for (int j = 0; j < 4; ++j)
#pragma unroll
        for (int r = 0; r < 4; ++r) {
          const _Float16 hv = (_Float16)sv[j][r];
          *(short*)(Cb + (size_t)(rowbase + i * 16 + r) * 8192 + 4096 +
                    (size_t)(colbase + j * 16) * 2) = __builtin_bit_cast(short, hv);
        }
      // per-row partial (max, sum-exp) over this wave's 64 cols (exact fp32)
#pragma unroll
      for (int r = 0; r < 4; ++r) {
        float mx = fmaxf(fmaxf(sv[0][r], sv[1][r]), fmaxf(sv[2][r], sv[3][r]));
#pragma unroll
        for (int off = 1; off < 16; off <<= 1) mx = fmaxf(mx, __shfl_xor(mx, off, 64));
        float sm = __expf(sv[0][r] - mx) + __expf(sv[1][r] - mx) +
                   __expf(sv[2][r] - mx) + __expf(sv[3][r] - mx);
#pragma unroll
        for (int off = 1; off < 16; off <<= 1) sm += __shfl_xor(sm, off, 64);
        if ((lane & 15) == 0)
          ps[(size_t)(rowbase + i * 16 + r) * 32 + pid] = make_float2(mx, sm);
      }
    }
  } else {  // M_OUT: fp32 partial (kq) into ws
    float* C = (float*)Cp + (size_t)((bz & 3) * 2 + (bz >> 2)) * ((size_t)cL * cD);
#pragma unroll
    for (int i = 0; i < 4; ++i)
#pragma unroll
      for (int j = 0; j < 4; ++j)
#pragma unroll
        for (int r = 0; r < 4; ++r)
          C[(size_t)(rowbase + i * 16 + r) * cD + (colbase + j * 16)] = acc[i][j][r];
  }
}

// ---------------- fused softmax-normalize + ctx (fp16 S in place) -----------
// grid 512 (1-D, XCD-decoded: XCD x owns z in {2x,2x+1}) = 2 blocks/CU.
// 512 threads = 8 N-waves, block tile 64 rows x 512 e. Pipelined: dbuf Bs/Pb,
// DMA one tile ahead, ONE s_barrier/tile with counted vmcnt(2). Prologue
// folds combine_stats. S loads PLAIN (L3-resident); attn stores nt (final
// output, never re-read - don't evict S/vhT).
__global__ __launch_bounds__(512, 4) void fused_ctx(const short* __restrict__ vhT,
                                                    const float2* __restrict__ pstats,
                                                    float* __restrict__ attn,
                                                    short* __restrict__ comb) {
  __shared__ short Bs[2][512 * 32];  // 64 KB vhT tiles (dbuf), swizzled
  __shared__ short Pb[2][64 * 32];   //  8 KB P bf16 (dbuf), swizzled

  const int t = threadIdx.x;
  const int lane = t & 63;
  const int wv = t >> 6;          // 0..7 (N-wave)
  // ---- XCD decode: li&7 = XCD, owns z = xcd*2 + (s>>5), rowblk = s&31 ----
  const int li = blockIdx.x;
  const int sfl = li >> 3;
  const int z = (li & 7) * 2 + (sfl >> 5);
  const int rowblk = sfl & 31;    // 0..31

  // transform-thread coords: thread owns (row = t>>3, 4-col chunk t&7 per tile)
  const int trow = t >> 3;                       // 0..63
  const int tcb = t & 7;                         // which 4-col piece in 32-tile
  const int pidx = trow * 32 + (((tcb >> 1) ^ ((trow >> 1) & 3)) << 3) + ((tcb & 1) << 2);
  const int grow = rowblk * 64 + trow;

  // ---- folded combine_stats: (m, 1/l) from 32 partials, 8 threads/row ----
  const float2* pp = pstats + ((size_t)z * cL + grow) * 32 + tcb * 4;
  const float2 q0 = pp[0], q1 = pp[1], q2 = pp[2], q3 = pp[3];
  float m = fmaxf(fmaxf(q0.x, q1.x), fmaxf(q2.x, q3.x));
#pragma unroll
  for (int off = 1; off < 8; off <<= 1) m = fmaxf(m, __shfl_xor(m, off, 64));
  float l = q0.y * __expf(q0.x - m) + q1.y * __expf(q1.x - m) +
            q2.y * __expf(q2.x - m) + q3.y * __expf(q3.x - m);
#pragma unroll
  for (int off = 1; off < 8; off <<= 1) l += __shfl_xor(l, off, 64);
  const float invl = 1.0f / l;

  char* rowb = (char*)attn + ((size_t)z << 24) + (size_t)grow * 8192;
  float* spf = (float*)rowb + tcb * 4;          // fp32 attn out (lower 8KB slot)
  const h4* sph = (const h4*)(rowb + 4096);     // fp16 S (upper 4KB); idx tcb+k*8

  const short* Bg = vhT + (size_t)z * ((size_t)cD * cL);

  f32x4 acc[4][4];
#pragma unroll
  for (int i = 0; i < 4; ++i)
#pragma unroll
    for (int j = 0; j < 4; ++j) acc[i][j] = (f32x4){0.f, 0.f, 0.f, 0.f};

  const int qk = lane >> 4;                  // frag k-chunk 0..3
  const int arr = lane & 15;
  const int br = wv * 64 + (lane & 15);

  auto stageB = [&](int nb, int kt) {
#pragma unroll
    for (int r = 0; r < 4; ++r) {
      const int cbase = r * 512 + wv * 64;   // wave-uniform base
      const int c = cbase + lane;            // 0..2047 16B chunks
      const int row = c >> 2;
      const int swcol = ((c & 3) ^ ((row >> 1) & 3)) * 8;  // source pre-swizzle
      gload16(Bg + (size_t)row * cL + kt + swcol, &Bs[nb][cbase * 8]);
    }
  };
  auto transform = [&](int ck, h4 hv) -> short4v {
    const float p0 = __expf((float)hv[0] - m) * invl;
    const float p1 = __expf((float)hv[1] - m) * invl;
    const float p2 = __expf((float)hv[2] - m) * invl;
    const float p3 = __expf((float)hv[3] - m) * invl;
    __builtin_nontemporal_store((f32x4){p0, p1, p2, p3}, (f32x4*)(spf + ck * 32));
    short4v pb = { f2bf(p0), f2bf(p1), f2bf(p2), f2bf(p3) };
    return pb;
  };

  // ---- prologue: DMA tile 0; transform chunk 0 -> Pb[0] ----
  stageB(0, 0);
  h4 hc = sph[tcb];                                     // tile 0 (plain load)
  short4v pb = transform(0, hc);
  hc = sph[tcb + 8];                                    // tile 1
  *(short4v*)&Pb[0][pidx] = pb;

  for (int k = 0; k < 63; ++k) {
    const int cb = k & 1, nb = cb ^ 1;
    // s1: transform chunk k+1 (VALU + 1 attn store), prefetch chunk (k+2)&63
    pb = transform(k + 1, hc);
    const int kc = (k + 2) & 63;   // k=62 wraps to chunk 0: dead load, keeps count
    hc = sph[tcb + kc * 8];
    // s2: tile-k DMA done (2 newest vm ops = this iter's store + load);
    //     my ds ops drained for barrier visibility
    asm volatile("s_waitcnt vmcnt(2) lgkmcnt(0)" ::: "memory");
    __builtin_amdgcn_sched_barrier(0);
    // s3: the ONLY barrier per tile (no vmcnt(0) drain)
    __builtin_amdgcn_s_barrier();
    __builtin_amdgcn_sched_barrier(0);
    // s4: publish P tile k+1 (readers are behind next barrier)
    *(short4v*)&Pb[nb][pidx] = pb;
    // s5: DMA tile k+1 (WAR-safe: all tile-k-1 readers passed this barrier)
    stageB(nb, (k + 1) * 32);
    __builtin_amdgcn_sched_barrier(0);  // pin DMA before compute: vmcnt(2) has 0 slack
    // s6: compute tile k
    bf16x8 af[4], bfv[4];
#pragma unroll
    for (int i = 0; i < 4; ++i) {
      const int rA = arr + i * 16;
      af[i] = *(const bf16x8*)&Pb[cb][rA * 32 + ((qk ^ ((rA >> 1) & 3)) << 3)];
    }
#pragma unroll
    for (int j = 0; j < 4; ++j) {
      const int rB = br + j * 16;
      bfv[j] = *(const bf16x8*)&Bs[cb][rB * 32 + ((qk ^ ((rB >> 1) & 3)) << 3)];
    }
    __builtin_amdgcn_s_setprio(1);
#pragma unroll
    for (int i = 0; i < 4; ++i)
#pragma unroll
      for (int j = 0; j < 4; ++j)
        acc[i][j] = __builtin_amdgcn_mfma_f32_16x16x32_bf16(af[i], bfv[j], acc[i][j], 0, 0, 0);
    __builtin_amdgcn_s_setprio(0);
  }

  // ---- peeled tile 63 (buffers 1) ----
  asm volatile("s_waitcnt vmcnt(0) lgkmcnt(0)" ::: "memory");
  __builtin_amdgcn_sched_barrier(0);
  __builtin_amdgcn_s_barrier();
  __builtin_amdgcn_sched_barrier(0);
  {
    bf16x8 af[4], bfv[4];
#pragma unroll
    for (int i = 0; i < 4; ++i) {
      const int rA = arr + i * 16;
      af[i] = *(const bf16x8*)&Pb[1][rA * 32 + ((qk ^ ((rA >> 1) & 3)) << 3)];
    }
#pragma unroll
    for (int j = 0; j < 4; ++j) {
      const int rB = br + j * 16;
      bfv[j] = *(const bf16x8*)&Bs[1][rB * 32 + ((qk ^ ((rB >> 1) & 3)) << 3)];
    }
    __builtin_amdgcn_s_setprio(1);
#pragma unroll
    for (int i = 0; i < 4; ++i)
#pragma unroll
      for (int j = 0; j < 4; ++j)
        acc[i][j] = __builtin_amdgcn_mfma_f32_16x16x32_bf16(af[i], bfv[j], acc[i][j], 0, 0, 0);
    __builtin_amdgcn_s_setprio(0);
  }

  // ---- epilogue -> comb permuted layout: j = (e>>6)*512 + h*64 + (e&63) ----
  const int r0 = (lane >> 4) * 4;
  const int cc = lane & 15;
  short* C = comb + (size_t)(z >> 3) * ((size_t)cL * (cH * cD));
  const int h = z & 7;
  const int rowbase = rowblk * 64 + r0;
#pragma unroll
  for (int i = 0; i < 4; ++i)
#pragma unroll
    for (int j = 0; j < 4; ++j) {
      const int e = wv * 64 + j * 16 + cc;
      const int jc = ((e >> 6) << 9) + (h << 6) + (e & 63);
#pragma unroll
      for (int r = 0; r < 4; ++r)
        C[(size_t)(rowbase + i * 16 + r) * (cH * cD) + jc] = f2bf(acc[i][j][r]);
    }
}

// --------------------- sum the four split-K partials ------------------------
__global__ __launch_bounds__(256) void add_quads(const float* __restrict__ p,
                                                 float* __restrict__ out) {
  const int i = blockIdx.x * 256 + threadIdx.x;
  constexpr int S = cB * cL * cD;  // floats per partial
  const f32x4 a = __builtin_nontemporal_load((const f32x4*)p + i);
  const f32x4 b = __builtin_nontemporal_load((const f32x4*)(p + S) + i);
  const f32x4 c = __builtin_nontemporal_load((const f32x4*)(p + 2 * S) + i);
  const f32x4 d = __builtin_nontemporal_load((const f32x4*)(p + 3 * S) + i);
  const f32x4 s = a + b + c + d;
  *((f32x4*)out + i) = s;
}

// --------------------------------- launch -----------------------------------
extern "C" void kernel_launch(void* const* d_in, const int* in_sizes, int n_in,
                              void* d_out, int out_size, void* d_ws, size_t ws_size,
                              hipStream_t stream) {
  (void)in_sizes; (void)n_in; (void)out_size;

  const float* q  = (const float*)d_in[0];
  const float* k  = (const float*)d_in[1];
  const float* v  = (const float*)d_in[2];
  const float* Wq = (const float*)d_in[3];
  const float* Wk = (const float*)d_in[4];
  const float* Wv = (const float*)d_in[5];
  const float* Wo = (const float*)d_in[6];

  float* out  = (float*)d_out;
  float* attn = out + (size_t)cB * cL * cD;  // 2,097,152 floats in

  constexpr size_t Mi = 1ull << 20;
  char* ws = (char*)d_ws;
  short* qbf = (short*)(ws + 0 * Mi);
  short* kbf = (short*)(ws + 4 * Mi);
  short* vbf = (short*)(ws + 8 * Mi);
  short* wqb = (short*)(ws + 12 * Mi);
  short* wkb = (short*)(ws + 16 * Mi);
  short* wvb = (short*)(ws + 20 * Mi);
  short* wob = (short*)(ws + 24 * Mi);
  short* qh  = (short*)(ws + 28 * Mi);   // 32 MiB; dead after scores
  short* kh  = (short*)(ws + 60 * Mi);   // 32 MiB; dead after scores
  short* vhT = (short*)(ws + 92 * Mi);   // 32 MiB
  short* comb = qh;                      // alias: written after qh dead
  float2* pstats = (float2*)(ws + 4 * Mi);  // 8 MiB, alias kbf+vbf (dead after proj)
  float*  pout   = (float*)(ws + 60 * Mi);  // alias kh (dead after scores), 32 MiB

  if (ws_size < 124 * Mi) {
    fprintf(stderr, "kernel_launch: ws too small (%zu < %zu)\n", ws_size, 124 * Mi);
    return;
  }

  // 1) convert inputs/weights to bf16 (7 same-size tensors, one launch)
  CvtArgs ca;
  ca.s[0] = (const float4*)q;  ca.d[0] = (short4v*)qbf;
  ca.s[1] = (const float4*)k;  ca.d[1] = (short4v*)kbf;
  ca.s[2] = (const float4*)v;  ca.d[2] = (short4v*)vbf;
  ca.s[3] = (const float4*)Wq; ca.d[3] = (short4v*)wqb;
  ca.s[4] = (const float4*)Wk; ca.d[4] = (short4v*)wkb;
  ca.s[5] = (const float4*)Wv; ca.d[5] = (short4v*)wvb;
  ca.s[6] = (const float4*)Wo; ca.d[6] = (short4v*)wob;
  cvt_all<<<dim3(2048, 7), 256, 0, stream>>>(ca);

  // 2) per-head projections (z = b*8+h), M=2048 N=512 K=512
  gemm_nt<M_PROJ ><<<dim3(4, 16, 16), 256, 0, stream>>>(qbf, wqb, qh, nullptr);
  gemm_nt<M_PROJ ><<<dim3(4, 16, 16), 256, 0, stream>>>(kbf, wkb, kh, nullptr);
  gemm_nt<M_PROJV><<<dim3(4, 16, 16), 256, 0, stream>>>(vbf, wvb, vhT, nullptr);

  // 3) scores -> fp16 in attn region upper-row-halves + row-stats partials
  gemm_nt<M_SCORES><<<dim3(16, 16, 16), 256, 0, stream>>>(qh, kh, attn, pstats);

  // 4) fused: stats-combine + normalize (fp16 S -> fp32 attn in place) + ctx
  fused_ctx<<<dim3(512), 512, 0, stream>>>(vhT, pstats, attn, comb);

  // 5) out = comb @ Wo^T, split-K x4 (z = b*4 + kq) -> fp32 partials
  gemm_nt<M_OUT><<<dim3(4, 16, 8), 256, 0, stream>>>(comb, wob, (void*)pout, nullptr);

  // 6) out = sum of 4 partials
  add_quads<<<2048, 256, 0, stream>>>(pout, out);
}